// Round 1
// baseline (575.013 us; speedup 1.0000x reference)
//
#include <hip/hip_runtime.h>
#include <hip/hip_bf16.h>
#include <math.h>

// Problem constants (from reference setup_inputs)
#define B_ 32
#define S_ 1024
#define E_ 512
#define T_ 128
#define Q_ 256
#define H_ 4
#define F_ (H_ * Q_)      // 1024
#define M_ (B_ * S_)      // 32768

__device__ __forceinline__ float lrelu(float x) { return x > 0.0f ? x : 0.01f * x; }

// ---------------------------------------------------------------------------
// Kernel A: options_scores = q . W_opt^T, argmax over heads, build per-(b,h)
// lists of t indices (order irrelevant — each t writes its own output rows).
// ---------------------------------------------------------------------------
__global__ __launch_bounds__(256) void head_select_kernel(
    const float* __restrict__ qv,    // (T,B,Q)
    const float* __restrict__ Wopt,  // (H,Q)
    int* __restrict__ cnt,           // (B*H), pre-zeroed
    int* __restrict__ lists)         // (B*H*T)
{
    int idx = blockIdx.x * blockDim.x + threadIdx.x;   // t*B + b
    if (idx >= T_ * B_) return;
    int t = idx >> 5;          // / B_
    int b = idx & (B_ - 1);
    const float* q = qv + (size_t)idx * Q_;
    float s0 = 0.f, s1 = 0.f, s2 = 0.f, s3 = 0.f;
    for (int i = 0; i < Q_; i += 4) {
        float4 qq = *(const float4*)(q + i);
        float4 w0 = *(const float4*)(Wopt + 0 * Q_ + i);
        float4 w1 = *(const float4*)(Wopt + 1 * Q_ + i);
        float4 w2 = *(const float4*)(Wopt + 2 * Q_ + i);
        float4 w3 = *(const float4*)(Wopt + 3 * Q_ + i);
        s0 += qq.x * w0.x + qq.y * w0.y + qq.z * w0.z + qq.w * w0.w;
        s1 += qq.x * w1.x + qq.y * w1.y + qq.z * w1.z + qq.w * w1.w;
        s2 += qq.x * w2.x + qq.y * w2.y + qq.z * w2.z + qq.w * w2.w;
        s3 += qq.x * w3.x + qq.y * w3.y + qq.z * w3.z + qq.w * w3.w;
    }
    // argmax, first occurrence on ties (strict >)
    int bh = 0; float bs = s0;
    if (s1 > bs) { bs = s1; bh = 1; }
    if (s2 > bs) { bs = s2; bh = 2; }
    if (s3 > bs) { bs = s3; bh = 3; }
    int slot = atomicAdd(&cnt[b * H_ + bh], 1);
    lists[(b * H_ + bh) * T_ + slot] = t;
}

// ---------------------------------------------------------------------------
// Kernel B: proj = leaky_relu(src @ W_src^T), stored in (B,H,S,Q) layout.
// fp32 GEMM: M=32768, N=1024, K=512. 128x128 block tile, 8x8 micro-tile.
// Both operands are K-contiguous (row-major over E), staged K-transposed.
// ---------------------------------------------------------------------------
__global__ __launch_bounds__(256) void proj_kernel(
    const float* __restrict__ A,   // (M_, E_) = src_encodings
    const float* __restrict__ W,   // (F_, E_) = W_src
    float* __restrict__ P)         // (B_,H_,S_,Q_)
{
    __shared__ float As[16][132];
    __shared__ float Ws[16][132];
    const int bi = blockIdx.y;     // 0..255  (M/128)
    const int bj = blockIdx.x;     // 0..7    (N/128)
    const int tid = threadIdx.x;
    const int tx = tid & 15;       // col group
    const int ty = tid >> 4;       // row group
    const int lrow = tid >> 1;     // 0..127 staging row
    const int lk = (tid & 1) * 8;  // 0 or 8 staging k offset

    const float* Ap = A + ((size_t)(bi * 128 + lrow)) * E_ + lk;
    const float* Wp = W + ((size_t)(bj * 128 + lrow)) * E_ + lk;

    float acc[8][8] = {};

    for (int k0 = 0; k0 < E_; k0 += 16) {
        float4 a0 = *(const float4*)(Ap + k0);
        float4 a1 = *(const float4*)(Ap + k0 + 4);
        float4 w0 = *(const float4*)(Wp + k0);
        float4 w1 = *(const float4*)(Wp + k0 + 4);
        __syncthreads();
        As[lk + 0][lrow] = a0.x; As[lk + 1][lrow] = a0.y;
        As[lk + 2][lrow] = a0.z; As[lk + 3][lrow] = a0.w;
        As[lk + 4][lrow] = a1.x; As[lk + 5][lrow] = a1.y;
        As[lk + 6][lrow] = a1.z; As[lk + 7][lrow] = a1.w;
        Ws[lk + 0][lrow] = w0.x; Ws[lk + 1][lrow] = w0.y;
        Ws[lk + 2][lrow] = w0.z; Ws[lk + 3][lrow] = w0.w;
        Ws[lk + 4][lrow] = w1.x; Ws[lk + 5][lrow] = w1.y;
        Ws[lk + 6][lrow] = w1.z; Ws[lk + 7][lrow] = w1.w;
        __syncthreads();
#pragma unroll
        for (int k = 0; k < 16; ++k) {
            float a[8], w[8];
            *(float4*)&a[0] = *(const float4*)&As[k][ty * 8];
            *(float4*)&a[4] = *(const float4*)&As[k][ty * 8 + 4];
            *(float4*)&w[0] = *(const float4*)&Ws[k][tx * 8];
            *(float4*)&w[4] = *(const float4*)&Ws[k][tx * 8 + 4];
#pragma unroll
            for (int i = 0; i < 8; ++i)
#pragma unroll
                for (int j = 0; j < 8; ++j)
                    acc[i][j] += a[i] * w[j];
        }
    }

    // Epilogue: leaky_relu, store to (B,H,S,Q). Each 128-col tile lies within
    // one head (head boundary = 256, tile = 128).
    const int i0 = bi * 128 + ty * 8;   // global row (= b*S + s)
    const int f0 = bj * 128 + tx * 8;   // global col (= h*Q + q)
    const int h = f0 >> 8;
    const int q = f0 & (Q_ - 1);
#pragma unroll
    for (int i = 0; i < 8; ++i) {
        int gi = i0 + i;
        int b = gi >> 10;
        int s = gi & (S_ - 1);
        float* dst = P + (((size_t)(b * H_ + h)) * S_ + s) * Q_ + q;
        float4 v0, v1;
        v0.x = lrelu(acc[i][0]); v0.y = lrelu(acc[i][1]);
        v0.z = lrelu(acc[i][2]); v0.w = lrelu(acc[i][3]);
        v1.x = lrelu(acc[i][4]); v1.y = lrelu(acc[i][5]);
        v1.z = lrelu(acc[i][6]); v1.w = lrelu(acc[i][7]);
        *(float4*)dst = v0;
        *(float4*)(dst + 4) = v1;
    }
}

// ---------------------------------------------------------------------------
// Kernel C: for each (b,h), w[t,b,s] = proj[b,h,s,:] . query[t,b,:] for the
// t's routed to head h. Tiled GEMM: 128(s) x 32(t-chunk), K=256.
// Writes unnormalized logits directly into d_out (T,B,S).
// ---------------------------------------------------------------------------
__global__ __launch_bounds__(256) void score_kernel(
    const float* __restrict__ P,      // (B,H,S,Q)
    const float* __restrict__ qv,     // (T,B,Q)
    const int* __restrict__ cnt,      // (B*H)
    const int* __restrict__ lists,    // (B*H*T)
    float* __restrict__ out)          // (T,B,S)
{
    __shared__ float Ps[16][132];
    __shared__ float Qs[16][36];
    __shared__ int tl[32];

    const int bx = blockIdx.x;        // B*H*8 = 1024 blocks
    const int stile = bx & 7;
    const int h = (bx >> 3) & 3;
    const int b = bx >> 5;
    const int tid = threadIdx.x;
    const int sx = tid & 15;          // s group (16 x 8 = 128)
    const int txx = tid >> 4;         // t group (16 x 2 = 32)
    const int lrow = tid >> 1;        // staging row 0..127
    const int lk = (tid & 1) * 8;

    const int n = cnt[b * H_ + h];
    const int* list = lists + (b * H_ + h) * T_;
    const int s0 = stile * 128;
    const float* Pbase = P + (((size_t)(b * H_ + h)) * S_ + s0) * Q_;

    const int jq = tid >> 2;          // query staging: j index 0..31 (tid<128)
    const int kq = (tid & 3) * 4;

    for (int tc = 0; tc < n; tc += 32) {
        int nn = min(32, n - tc);
        __syncthreads();   // protect tl vs previous chunk's readers
        if (tid < 32) tl[tid] = (tid < nn) ? list[tc + tid] : 0;
        __syncthreads();
        const float* qp = nullptr;
        if (tid < 128 && jq < nn)
            qp = qv + ((size_t)tl[jq] * B_ + b) * Q_ + kq;

        float acc[8][2] = {};
        for (int k0 = 0; k0 < Q_; k0 += 16) {
            const float* pp = Pbase + (size_t)lrow * Q_ + k0 + lk;
            float4 p0 = *(const float4*)pp;
            float4 p1 = *(const float4*)(pp + 4);
            float4 q0 = make_float4(0.f, 0.f, 0.f, 0.f);
            if (qp) q0 = *(const float4*)(qp + k0);
            __syncthreads();
            Ps[lk + 0][lrow] = p0.x; Ps[lk + 1][lrow] = p0.y;
            Ps[lk + 2][lrow] = p0.z; Ps[lk + 3][lrow] = p0.w;
            Ps[lk + 4][lrow] = p1.x; Ps[lk + 5][lrow] = p1.y;
            Ps[lk + 6][lrow] = p1.z; Ps[lk + 7][lrow] = p1.w;
            if (tid < 128) {
                Qs[kq + 0][jq] = q0.x; Qs[kq + 1][jq] = q0.y;
                Qs[kq + 2][jq] = q0.z; Qs[kq + 3][jq] = q0.w;
            }
            __syncthreads();
#pragma unroll
            for (int k = 0; k < 16; ++k) {
                float a[8];
                *(float4*)&a[0] = *(const float4*)&Ps[k][sx * 8];
                *(float4*)&a[4] = *(const float4*)&Ps[k][sx * 8 + 4];
                float2 qq = *(const float2*)&Qs[k][txx * 2];
#pragma unroll
                for (int i = 0; i < 8; ++i) {
                    acc[i][0] += a[i] * qq.x;
                    acc[i][1] += a[i] * qq.y;
                }
            }
        }
#pragma unroll
        for (int jc = 0; jc < 2; ++jc) {
            int jj = txx * 2 + jc;
            if (jj < nn) {
                int t = tl[jj];
                float* dst = out + ((size_t)t * B_ + b) * S_ + s0 + sx * 8;
                float4 v0 = make_float4(acc[0][jc], acc[1][jc], acc[2][jc], acc[3][jc]);
                float4 v1 = make_float4(acc[4][jc], acc[5][jc], acc[6][jc], acc[7][jc]);
                *(float4*)dst = v0;
                *(float4*)(dst + 4) = v1;
            }
        }
    }
}

// ---------------------------------------------------------------------------
// Kernel D: in-place masked softmax over S per (t,b) row.
// mask==true(!=0) -> -inf (masked OUT), softmax over axis S.
// ---------------------------------------------------------------------------
__global__ __launch_bounds__(256) void softmax_kernel(
    float* __restrict__ out,          // (T,B,S) logits in, probs out
    const int* __restrict__ mask)     // (B,S) as int32
{
    const int row = blockIdx.x;       // t*B + b
    const int b = row & (B_ - 1);
    float* w = out + (size_t)row * S_;
    const int* mrow = mask + (size_t)b * S_;
    const int tid = threadIdx.x;

    float4 v = *(const float4*)(w + tid * 4);
    int4 mm = *(const int4*)(mrow + tid * 4);
    float x0 = mm.x ? -INFINITY : v.x;
    float x1 = mm.y ? -INFINITY : v.y;
    float x2 = mm.z ? -INFINITY : v.z;
    float x3 = mm.w ? -INFINITY : v.w;

    float lmax = fmaxf(fmaxf(x0, x1), fmaxf(x2, x3));
#pragma unroll
    for (int off = 32; off >= 1; off >>= 1)
        lmax = fmaxf(lmax, __shfl_down(lmax, off));

    __shared__ float redmax[4];
    __shared__ float redsum[4];
    const int wave = tid >> 6, lane = tid & 63;
    if (lane == 0) redmax[wave] = lmax;
    __syncthreads();
    float gmax = fmaxf(fmaxf(redmax[0], redmax[1]), fmaxf(redmax[2], redmax[3]));

    float e0 = mm.x ? 0.f : __expf(x0 - gmax);
    float e1 = mm.y ? 0.f : __expf(x1 - gmax);
    float e2 = mm.z ? 0.f : __expf(x2 - gmax);
    float e3 = mm.w ? 0.f : __expf(x3 - gmax);
    float lsum = e0 + e1 + e2 + e3;
#pragma unroll
    for (int off = 32; off >= 1; off >>= 1)
        lsum += __shfl_down(lsum, off);
    if (lane == 0) redsum[wave] = lsum;
    __syncthreads();
    float gsum = redsum[0] + redsum[1] + redsum[2] + redsum[3];
    float rinv = 1.0f / gsum;

    float4 o = make_float4(e0 * rinv, e1 * rinv, e2 * rinv, e3 * rinv);
    *(float4*)(w + tid * 4) = o;
}

// ---------------------------------------------------------------------------
extern "C" void kernel_launch(void* const* d_in, const int* in_sizes, int n_in,
                              void* d_out, int out_size, void* d_ws, size_t ws_size,
                              hipStream_t stream) {
    const float* src  = (const float*)d_in[0];   // (B,S,E)
    const int*   mask = (const int*)d_in[1];     // (B,S) bool -> int32
    const float* qv   = (const float*)d_in[2];   // (T,B,Q)
    const float* Wsrc = (const float*)d_in[3];   // (H*Q, E)
    const float* Wopt = (const float*)d_in[4];   // (H, Q)
    float* out = (float*)d_out;                  // (T,B,S)

    // Workspace layout: proj (B,H,S,Q) fp32 = 128 MiB, then cnt, then lists.
    float* P = (float*)d_ws;
    const size_t P_bytes = (size_t)B_ * H_ * S_ * Q_ * sizeof(float);  // 134217728
    int* cnt = (int*)((char*)d_ws + P_bytes);
    int* lists = cnt + 256;  // B*H=128 counters, padded to 256

    hipMemsetAsync(cnt, 0, 128 * sizeof(int), stream);
    hipLaunchKernelGGL(head_select_kernel, dim3((T_ * B_ + 255) / 256), dim3(256), 0, stream,
                       qv, Wopt, cnt, lists);
    hipLaunchKernelGGL(proj_kernel, dim3(F_ / 128, M_ / 128), dim3(256), 0, stream,
                       src, Wsrc, P);
    hipLaunchKernelGGL(score_kernel, dim3(B_ * H_ * (S_ / 128)), dim3(256), 0, stream,
                       P, qv, cnt, lists, out);
    hipLaunchKernelGGL(softmax_kernel, dim3(T_ * B_), dim3(256), 0, stream,
                       out, mask);
}

// Round 2
// 354.203 us; speedup vs baseline: 1.6234x; 1.6234x over previous
//
#include <hip/hip_runtime.h>
#include <hip/hip_bf16.h>
#include <math.h>

#define B_ 32
#define S_ 1024
#define E_ 512
#define T_ 128
#define Q_ 256
#define H_ 4
#define F_ (H_ * Q_)      // 1024
#define M_ (B_ * S_)      // 32768

typedef __bf16 bf16x8 __attribute__((ext_vector_type(8)));
typedef float f32x4 __attribute__((ext_vector_type(4)));
typedef unsigned int uint32;

__device__ __forceinline__ float lrelu(float x) { return x > 0.0f ? x : 0.01f * x; }

#define GLOAD_LDS16(g, l)                                                       \
    __builtin_amdgcn_global_load_lds(                                           \
        (const __attribute__((address_space(1))) void*)(g),                     \
        (__attribute__((address_space(3))) void*)(l), 16, 0, 0)

// ---------------------------------------------------------------------------
// Repack fp32 rows in-place: each 256B window (64 floats) becomes
// 128B of bf16 hi (truncated) + 128B of bf16 lo (residual, truncated).
// Same total bytes; enables global_load_lds staging of hi/lo tiles.
// Each thread owns one 256B window exclusively (loads fully precede stores).
// ---------------------------------------------------------------------------
__global__ __launch_bounds__(256) void repack_kernel(float* x, int nchunks) {
    int c = blockIdx.x * blockDim.x + threadIdx.x;
    if (c >= nchunks) return;
    float4* p = (float4*)(x + (size_t)c * 64);
    float4 v[16];
#pragma unroll
    for (int i = 0; i < 16; ++i) v[i] = p[i];
    uint32 hi[32], lo[32];
#pragma unroll
    for (int i = 0; i < 16; ++i) {
        float f[4] = {v[i].x, v[i].y, v[i].z, v[i].w};
        uint32 h[4], l[4];
#pragma unroll
        for (int e = 0; e < 4; ++e) {
            uint32 u = __float_as_uint(f[e]);
            h[e] = u >> 16;
            float rem = f[e] - __uint_as_float(u & 0xffff0000u);
            l[e] = __float_as_uint(rem) >> 16;
        }
        hi[2 * i]     = h[0] | (h[1] << 16);
        hi[2 * i + 1] = h[2] | (h[3] << 16);
        lo[2 * i]     = l[0] | (l[1] << 16);
        lo[2 * i + 1] = l[2] | (l[3] << 16);
    }
    uint4* o = (uint4*)(x + (size_t)c * 64);
#pragma unroll
    for (int i = 0; i < 8; ++i) o[i] = make_uint4(hi[4*i], hi[4*i+1], hi[4*i+2], hi[4*i+3]);
#pragma unroll
    for (int i = 0; i < 8; ++i) o[8+i] = make_uint4(lo[4*i], lo[4*i+1], lo[4*i+2], lo[4*i+3]);
}

// ---------------------------------------------------------------------------
// Kernel A: head routing (unchanged from round 1).
// ---------------------------------------------------------------------------
__global__ __launch_bounds__(256) void head_select_kernel(
    const float* __restrict__ qv, const float* __restrict__ Wopt,
    int* __restrict__ cnt, int* __restrict__ lists) {
    int idx = blockIdx.x * blockDim.x + threadIdx.x;
    if (idx >= T_ * B_) return;
    int t = idx >> 5;
    int b = idx & (B_ - 1);
    const float* q = qv + (size_t)idx * Q_;
    float s0 = 0.f, s1 = 0.f, s2 = 0.f, s3 = 0.f;
    for (int i = 0; i < Q_; i += 4) {
        float4 qq = *(const float4*)(q + i);
        float4 w0 = *(const float4*)(Wopt + 0 * Q_ + i);
        float4 w1 = *(const float4*)(Wopt + 1 * Q_ + i);
        float4 w2 = *(const float4*)(Wopt + 2 * Q_ + i);
        float4 w3 = *(const float4*)(Wopt + 3 * Q_ + i);
        s0 += qq.x * w0.x + qq.y * w0.y + qq.z * w0.z + qq.w * w0.w;
        s1 += qq.x * w1.x + qq.y * w1.y + qq.z * w1.z + qq.w * w1.w;
        s2 += qq.x * w2.x + qq.y * w2.y + qq.z * w2.z + qq.w * w2.w;
        s3 += qq.x * w3.x + qq.y * w3.y + qq.z * w3.z + qq.w * w3.w;
    }
    int bh = 0; float bs = s0;
    if (s1 > bs) { bs = s1; bh = 1; }
    if (s2 > bs) { bs = s2; bh = 2; }
    if (s3 > bs) { bs = s3; bh = 3; }
    int slot = atomicAdd(&cnt[b * H_ + bh], 1);
    lists[(b * H_ + bh) * T_ + slot] = t;
}

// ---------------------------------------------------------------------------
// Kernel B: proj = leaky_relu(src @ W^T) via split-bf16 3-MFMA.
// M=32768, N=1024, K=512. 128x128 block tile, 4 waves each 64x64.
// Inputs are repacked (hi|lo per 64-elem k-chunk, row stride 2048 B).
// global_load_lds width-16 staging into 4 LDS buffers (64 KB).
// ---------------------------------------------------------------------------
__global__ __launch_bounds__(256, 2) void proj_kernel(
    const unsigned char* __restrict__ Apk,   // repacked src
    const unsigned char* __restrict__ Wpk,   // repacked W_src
    float* __restrict__ P)                   // (B,H,S,Q) fp32
{
    __shared__ __bf16 Ah[128 * 64];
    __shared__ __bf16 Al[128 * 64];
    __shared__ __bf16 Bh[128 * 64];
    __shared__ __bf16 Bl[128 * 64];

    const int bj = blockIdx.x;   // 0..7   (N tiles)
    const int bi = blockIdx.y;   // 0..255 (M tiles)
    const int tid = threadIdx.x;
    const int wave = tid >> 6, lane = tid & 63;
    const int wm = wave >> 1, wn = wave & 1;
    const int srow = lane >> 3;            // staging row-in-chunk 0..7
    const int sboff = (lane & 7) * 16;     // staging byte off in 128B hi block
    const int quad = lane >> 4;            // 0..3
    const int fr = lane & 15;              // fragment row index

    const size_t Abase = (size_t)(bi * 128) * 2048;
    const size_t Wbase = (size_t)(bj * 128) * 2048;

    f32x4 acc[4][4] = {};

    for (int kc = 0; kc < 8; ++kc) {       // k0 = kc*64
        const size_t koff = (size_t)kc * 256;
        __syncthreads();
#pragma unroll
        for (int c = 0; c < 4; ++c) {
            int chunk = wave * 4 + c;      // 0..15, 8 rows each
            int row = chunk * 8 + srow;
            const unsigned char* ga = Apk + Abase + (size_t)row * 2048 + koff + sboff;
            const unsigned char* gw = Wpk + Wbase + (size_t)row * 2048 + koff + sboff;
            GLOAD_LDS16(ga,        &Ah[chunk * 512]);
            GLOAD_LDS16(ga + 128,  &Al[chunk * 512]);
            GLOAD_LDS16(gw,        &Bh[chunk * 512]);
            GLOAD_LDS16(gw + 128,  &Bl[chunk * 512]);
        }
        __syncthreads();
#pragma unroll
        for (int kk = 0; kk < 2; ++kk) {
            const int kof = kk * 32 + quad * 8;
            bf16x8 ah[4], al[4], bh[4], bl[4];
#pragma unroll
            for (int i = 0; i < 4; ++i) {
                int ra = (wm * 64 + i * 16 + fr) * 64 + kof;
                int rb = (wn * 64 + i * 16 + fr) * 64 + kof;
                ah[i] = *(const bf16x8*)&Ah[ra];
                al[i] = *(const bf16x8*)&Al[ra];
                bh[i] = *(const bf16x8*)&Bh[rb];
                bl[i] = *(const bf16x8*)&Bl[rb];
            }
#pragma unroll
            for (int i = 0; i < 4; ++i)
#pragma unroll
                for (int j = 0; j < 4; ++j) {
                    acc[i][j] = __builtin_amdgcn_mfma_f32_16x16x32_bf16(ah[i], bh[j], acc[i][j], 0, 0, 0);
                    acc[i][j] = __builtin_amdgcn_mfma_f32_16x16x32_bf16(ah[i], bl[j], acc[i][j], 0, 0, 0);
                    acc[i][j] = __builtin_amdgcn_mfma_f32_16x16x32_bf16(al[i], bh[j], acc[i][j], 0, 0, 0);
                }
        }
    }

    // Epilogue: D[m = quad*4+r][n = fr] per 16x16 tile; leaky_relu; (B,H,S,Q).
#pragma unroll
    for (int i = 0; i < 4; ++i) {
        int gmb = bi * 128 + wm * 64 + i * 16 + quad * 4;
#pragma unroll
        for (int j = 0; j < 4; ++j) {
            int gf = bj * 128 + wn * 64 + j * 16 + fr;
            int h = gf >> 8, q = gf & (Q_ - 1);
#pragma unroll
            for (int r = 0; r < 4; ++r) {
                int gm = gmb + r;
                int b = gm >> 10, s = gm & (S_ - 1);
                P[(((size_t)(b * H_ + h)) * S_ + s) * Q_ + q] = lrelu(acc[i][j][r]);
            }
        }
    }
}

// ---------------------------------------------------------------------------
// Kernel C: gathered scores (unchanged from round 1).
// ---------------------------------------------------------------------------
__global__ __launch_bounds__(256) void score_kernel(
    const float* __restrict__ P, const float* __restrict__ qv,
    const int* __restrict__ cnt, const int* __restrict__ lists,
    float* __restrict__ out) {
    __shared__ float Ps[16][132];
    __shared__ float Qs[16][36];
    __shared__ int tl[32];

    const int bx = blockIdx.x;
    const int stile = bx & 7;
    const int h = (bx >> 3) & 3;
    const int b = bx >> 5;
    const int tid = threadIdx.x;
    const int sx = tid & 15;
    const int txx = tid >> 4;
    const int lrow = tid >> 1;
    const int lk = (tid & 1) * 8;

    const int n = cnt[b * H_ + h];
    const int* list = lists + (b * H_ + h) * T_;
    const int s0 = stile * 128;
    const float* Pbase = P + (((size_t)(b * H_ + h)) * S_ + s0) * Q_;

    const int jq = tid >> 2;
    const int kq = (tid & 3) * 4;

    for (int tc = 0; tc < n; tc += 32) {
        int nn = min(32, n - tc);
        __syncthreads();
        if (tid < 32) tl[tid] = (tid < nn) ? list[tc + tid] : 0;
        __syncthreads();
        const float* qp = nullptr;
        if (tid < 128 && jq < nn)
            qp = qv + ((size_t)tl[jq] * B_ + b) * Q_ + kq;

        float acc[8][2] = {};
        for (int k0 = 0; k0 < Q_; k0 += 16) {
            const float* pp = Pbase + (size_t)lrow * Q_ + k0 + lk;
            float4 p0 = *(const float4*)pp;
            float4 p1 = *(const float4*)(pp + 4);
            float4 q0 = make_float4(0.f, 0.f, 0.f, 0.f);
            if (qp) q0 = *(const float4*)(qp + k0);
            __syncthreads();
            Ps[lk + 0][lrow] = p0.x; Ps[lk + 1][lrow] = p0.y;
            Ps[lk + 2][lrow] = p0.z; Ps[lk + 3][lrow] = p0.w;
            Ps[lk + 4][lrow] = p1.x; Ps[lk + 5][lrow] = p1.y;
            Ps[lk + 6][lrow] = p1.z; Ps[lk + 7][lrow] = p1.w;
            if (tid < 128) {
                Qs[kq + 0][jq] = q0.x; Qs[kq + 1][jq] = q0.y;
                Qs[kq + 2][jq] = q0.z; Qs[kq + 3][jq] = q0.w;
            }
            __syncthreads();
#pragma unroll
            for (int k = 0; k < 16; ++k) {
                float a[8];
                *(float4*)&a[0] = *(const float4*)&Ps[k][sx * 8];
                *(float4*)&a[4] = *(const float4*)&Ps[k][sx * 8 + 4];
                float2 qq = *(const float2*)&Qs[k][txx * 2];
#pragma unroll
                for (int i = 0; i < 8; ++i) {
                    acc[i][0] += a[i] * qq.x;
                    acc[i][1] += a[i] * qq.y;
                }
            }
        }
#pragma unroll
        for (int jc = 0; jc < 2; ++jc) {
            int jj = txx * 2 + jc;
            if (jj < nn) {
                int t = tl[jj];
                float* dst = out + ((size_t)t * B_ + b) * S_ + s0 + sx * 8;
                *(float4*)dst = make_float4(acc[0][jc], acc[1][jc], acc[2][jc], acc[3][jc]);
                *(float4*)(dst + 4) = make_float4(acc[4][jc], acc[5][jc], acc[6][jc], acc[7][jc]);
            }
        }
    }
}

// ---------------------------------------------------------------------------
// Kernel D: masked softmax (unchanged from round 1).
// ---------------------------------------------------------------------------
__global__ __launch_bounds__(256) void softmax_kernel(
    float* __restrict__ out, const int* __restrict__ mask) {
    const int row = blockIdx.x;
    const int b = row & (B_ - 1);
    float* w = out + (size_t)row * S_;
    const int* mrow = mask + (size_t)b * S_;
    const int tid = threadIdx.x;

    float4 v = *(const float4*)(w + tid * 4);
    int4 mm = *(const int4*)(mrow + tid * 4);
    float x0 = mm.x ? -INFINITY : v.x;
    float x1 = mm.y ? -INFINITY : v.y;
    float x2 = mm.z ? -INFINITY : v.z;
    float x3 = mm.w ? -INFINITY : v.w;

    float lmax = fmaxf(fmaxf(x0, x1), fmaxf(x2, x3));
#pragma unroll
    for (int off = 32; off >= 1; off >>= 1)
        lmax = fmaxf(lmax, __shfl_down(lmax, off));

    __shared__ float redmax[4];
    __shared__ float redsum[4];
    const int wave = tid >> 6, lane = tid & 63;
    if (lane == 0) redmax[wave] = lmax;
    __syncthreads();
    float gmax = fmaxf(fmaxf(redmax[0], redmax[1]), fmaxf(redmax[2], redmax[3]));

    float e0 = mm.x ? 0.f : __expf(x0 - gmax);
    float e1 = mm.y ? 0.f : __expf(x1 - gmax);
    float e2 = mm.z ? 0.f : __expf(x2 - gmax);
    float e3 = mm.w ? 0.f : __expf(x3 - gmax);
    float lsum = e0 + e1 + e2 + e3;
#pragma unroll
    for (int off = 32; off >= 1; off >>= 1)
        lsum += __shfl_down(lsum, off);
    if (lane == 0) redsum[wave] = lsum;
    __syncthreads();
    float gsum = redsum[0] + redsum[1] + redsum[2] + redsum[3];
    float rinv = 1.0f / gsum;

    *(float4*)(w + tid * 4) = make_float4(e0 * rinv, e1 * rinv, e2 * rinv, e3 * rinv);
}

// ---------------------------------------------------------------------------
extern "C" void kernel_launch(void* const* d_in, const int* in_sizes, int n_in,
                              void* d_out, int out_size, void* d_ws, size_t ws_size,
                              hipStream_t stream) {
    float* src  = (float*)d_in[0];               // (B,S,E) — repacked in-place
    const int* mask = (const int*)d_in[1];       // (B,S)
    const float* qv = (const float*)d_in[2];     // (T,B,Q)
    float* Wsrc = (float*)d_in[3];               // (H*Q,E) — repacked in-place
    const float* Wopt = (const float*)d_in[4];   // (H,Q)
    float* out = (float*)d_out;                  // (T,B,S)

    float* P = (float*)d_ws;                     // (B,H,S,Q) fp32, 128 MiB
    const size_t P_bytes = (size_t)B_ * H_ * S_ * Q_ * sizeof(float);
    int* cnt = (int*)((char*)d_ws + P_bytes);
    int* lists = cnt + 256;

    // In-place hi/lo repack of src (32768*8 chunks) and W_src (1024*8 chunks).
    hipLaunchKernelGGL(repack_kernel, dim3((M_ * 8 + 255) / 256), dim3(256), 0, stream,
                       src, M_ * 8);
    hipLaunchKernelGGL(repack_kernel, dim3((F_ * 8 + 255) / 256), dim3(256), 0, stream,
                       Wsrc, F_ * 8);

    hipMemsetAsync(cnt, 0, 128 * sizeof(int), stream);
    hipLaunchKernelGGL(head_select_kernel, dim3((T_ * B_ + 255) / 256), dim3(256), 0, stream,
                       qv, Wopt, cnt, lists);
    hipLaunchKernelGGL(proj_kernel, dim3(F_ / 128, M_ / 128), dim3(256), 0, stream,
                       (const unsigned char*)src, (const unsigned char*)Wsrc, P);
    hipLaunchKernelGGL(score_kernel, dim3(B_ * H_ * (S_ / 128)), dim3(256), 0, stream,
                       P, qv, cnt, lists, out);
    hipLaunchKernelGGL(softmax_kernel, dim3(T_ * B_), dim3(256), 0, stream,
                       out, mask);
}

// Round 3
// 276.745 us; speedup vs baseline: 2.0778x; 1.2799x over previous
//
#include <hip/hip_runtime.h>
#include <hip/hip_bf16.h>
#include <math.h>

#define B_ 32
#define S_ 1024
#define E_ 512
#define T_ 128
#define Q_ 256
#define H_ 4
#define F_ (H_ * Q_)      // 1024
#define M_ (B_ * S_)      // 32768

typedef __bf16 bf16x8 __attribute__((ext_vector_type(8)));
typedef float f32x4 __attribute__((ext_vector_type(4)));
typedef unsigned int uint32;

__device__ __forceinline__ float lrelu(float x) { return x > 0.0f ? x : 0.01f * x; }
__device__ __forceinline__ uint32 pack_hi2(float a, float b) {
    return (__float_as_uint(a) >> 16) | (__float_as_uint(b) & 0xffff0000u);
}
__device__ __forceinline__ float resid(float f) {
    return f - __uint_as_float(__float_as_uint(f) & 0xffff0000u);
}

#define GLOAD_LDS16(g, l)                                                       \
    __builtin_amdgcn_global_load_lds(                                           \
        (const __attribute__((address_space(1))) void*)(g),                     \
        (__attribute__((address_space(3))) void*)(l), 16, 0, 0)

// ---------------------------------------------------------------------------
// In-place hi/lo bf16 repack of fp32 rows (per 64-float window: 128B hi|128B lo)
// ---------------------------------------------------------------------------
__global__ __launch_bounds__(256) void repack_kernel(float* x, int nchunks) {
    int c = blockIdx.x * blockDim.x + threadIdx.x;
    if (c >= nchunks) return;
    float4* p = (float4*)(x + (size_t)c * 64);
    float4 v[16];
#pragma unroll
    for (int i = 0; i < 16; ++i) v[i] = p[i];
    uint32 hi[32], lo[32];
#pragma unroll
    for (int i = 0; i < 16; ++i) {
        float f[4] = {v[i].x, v[i].y, v[i].z, v[i].w};
        uint32 h[4], l[4];
#pragma unroll
        for (int e = 0; e < 4; ++e) {
            uint32 u = __float_as_uint(f[e]);
            h[e] = u >> 16;
            l[e] = __float_as_uint(f[e] - __uint_as_float(u & 0xffff0000u)) >> 16;
        }
        hi[2 * i] = h[0] | (h[1] << 16); hi[2 * i + 1] = h[2] | (h[3] << 16);
        lo[2 * i] = l[0] | (l[1] << 16); lo[2 * i + 1] = l[2] | (l[3] << 16);
    }
    uint4* o = (uint4*)(x + (size_t)c * 64);
#pragma unroll
    for (int i = 0; i < 8; ++i) o[i] = make_uint4(hi[4*i], hi[4*i+1], hi[4*i+2], hi[4*i+3]);
#pragma unroll
    for (int i = 0; i < 8; ++i) o[8+i] = make_uint4(lo[4*i], lo[4*i+1], lo[4*i+2], lo[4*i+3]);
}

// ---------------------------------------------------------------------------
// Head routing: one wave per (t,b). Shuffle-reduce 4 head dots, argmax, route.
// ---------------------------------------------------------------------------
__global__ __launch_bounds__(256) void head_select_kernel(
    const float* __restrict__ qv, const float* __restrict__ Wopt,
    int* __restrict__ cnt, int* __restrict__ lists) {
    const int wave = threadIdx.x >> 6, lane = threadIdx.x & 63;
    const int idx = blockIdx.x * 4 + wave;       // t*B + b, grid = 1024
    const int t = idx >> 5, b = idx & (B_ - 1);
    const float4 qq = *(const float4*)(qv + (size_t)idx * Q_ + lane * 4);
    float s[4];
#pragma unroll
    for (int h = 0; h < 4; ++h) {
        float4 w = *(const float4*)(Wopt + h * Q_ + lane * 4);
        s[h] = qq.x * w.x + qq.y * w.y + qq.z * w.z + qq.w * w.w;
    }
#pragma unroll
    for (int off = 32; off >= 1; off >>= 1) {
#pragma unroll
        for (int h = 0; h < 4; ++h) s[h] += __shfl_down(s[h], off);
    }
    if (lane == 0) {
        int bh = 0; float bs = s[0];
        if (s[1] > bs) { bs = s[1]; bh = 1; }
        if (s[2] > bs) { bs = s[2]; bh = 2; }
        if (s[3] > bs) { bs = s[3]; bh = 3; }
        int slot = atomicAdd(&cnt[b * H_ + bh], 1);
        lists[(b * H_ + bh) * T_ + slot] = t;
    }
}

// ---------------------------------------------------------------------------
// Fused proj+score. K-loop: split-bf16 3-MFMA GEMM (128m x 128n tile), LDS
// staging XOR-swizzled (granule g of row r lives at slot g^(r&7)) to kill the
// 8-way ds_read_b128 bank conflicts. Epilogue: acc -> hi/lo bf16 in LDS
// (reusing staging space), routed-query tiles staged per 32-t chunk, split
// MFMA (t x s over K=128 q), atomicAdd into out (2 q-half writers per elem).
// ---------------------------------------------------------------------------
__global__ __launch_bounds__(256, 2) void proj_score_kernel(
    const unsigned char* __restrict__ Apk,   // repacked src
    const unsigned char* __restrict__ Wpk,   // repacked W_src
    const float* __restrict__ qv,            // (T,B,Q) fp32
    const int* __restrict__ cnt,
    const int* __restrict__ lists,
    float* __restrict__ out)                 // (T,B,S), pre-zeroed
{
    __shared__ uint4 smem4[4096];            // 64 KB, carved below
    char* smem = (char*)smem4;
    // K-loop:   Ah [0,16K) Al [16K,32K) Bh [32K,48K) Bl [48K,64K)
    // Epilogue: Ph [0,16K) Pl [16K,32K) Qh [32K,40K) Ql [40K,48K) tl [48K,+512)

    const int bj = blockIdx.x;   // 0..7
    const int bi = blockIdx.y;   // 0..255
    const int tid = threadIdx.x;
    const int wave = tid >> 6, lane = tid & 63;
    const int wm = wave >> 1, wn = wave & 1;
    const int quad = lane >> 4;
    const int fr = lane & 15;
    const int xr = fr & 7;

    // staging: lane's LDS slot = lane; fetch global granule (lane&7)^(lane>>3)
    const int srow = lane >> 3;                       // row-in-chunk 0..7
    const int sgg = ((lane & 7) ^ srow) * 16;         // swizzled source granule

    const size_t Abase = (size_t)(bi * 128) * 2048;
    const size_t Wbase = (size_t)(bj * 128) * 2048;

    // frag-read byte offsets within a 128B row, kk = 0/1
    const int ko0 = ((quad ^ xr) & 7) * 16;
    const int ko1 = (((quad ^ 4) ^ xr) & 7) * 16;

    f32x4 acc[4][4] = {};

    for (int kc = 0; kc < 8; ++kc) {
        const size_t koff = (size_t)kc * 256;
        __syncthreads();
#pragma unroll
        for (int c = 0; c < 4; ++c) {
            int chunk = wave * 4 + c;                 // 0..15 (8 rows each)
            int row = chunk * 8 + srow;
            const unsigned char* ga = Apk + Abase + (size_t)row * 2048 + koff + sgg;
            const unsigned char* gw = Wpk + Wbase + (size_t)row * 2048 + koff + sgg;
            GLOAD_LDS16(ga,       smem +     chunk * 1024);
            GLOAD_LDS16(ga + 128, smem + 16384 + chunk * 1024);
            GLOAD_LDS16(gw,       smem + 32768 + chunk * 1024);
            GLOAD_LDS16(gw + 128, smem + 49152 + chunk * 1024);
        }
        __syncthreads();
#pragma unroll
        for (int kk = 0; kk < 2; ++kk) {
            const int ko = kk ? ko1 : ko0;
            bf16x8 ah[4], al[4], bh[4], bl[4];
#pragma unroll
            for (int i = 0; i < 4; ++i) {
                int ra = wm * 64 + i * 16 + fr;
                int rb = wn * 64 + i * 16 + fr;
                ah[i] = *(const bf16x8*)(smem +         ra * 128 + ko);
                al[i] = *(const bf16x8*)(smem + 16384 + ra * 128 + ko);
                bh[i] = *(const bf16x8*)(smem + 32768 + rb * 128 + ko);
                bl[i] = *(const bf16x8*)(smem + 49152 + rb * 128 + ko);
            }
#pragma unroll
            for (int i = 0; i < 4; ++i)
#pragma unroll
                for (int j = 0; j < 4; ++j) {
                    acc[i][j] = __builtin_amdgcn_mfma_f32_16x16x32_bf16(ah[i], bh[j], acc[i][j], 0, 0, 0);
                    acc[i][j] = __builtin_amdgcn_mfma_f32_16x16x32_bf16(ah[i], bl[j], acc[i][j], 0, 0, 0);
                    acc[i][j] = __builtin_amdgcn_mfma_f32_16x16x32_bf16(al[i], bh[j], acc[i][j], 0, 0, 0);
                }
        }
    }

    // ---- fused score epilogue ----
    const int b = bi >> 3;                 // 8 bi-tiles per b
    const int sbase = (bi & 7) * 128;      // s offset of this block
    const int h = bj >> 1;
    const int qoff = (bj & 1) * 128;       // q-half offset
    const int bh_idx = b * H_ + h;
    const int n = cnt[bh_idx];

    __syncthreads();                       // staging reads done; safe to reuse LDS
    int* tl = (int*)(smem + 49152);
    if (tid < 128) tl[tid] = lists[bh_idx * T_ + tid];

    const int t_idx = tid >> 3, seg = tid & 7;   // Q staging roles

    for (int half = 0; half < 2; ++half) {
        // write this wave's 64x128 acc quarter as hi/lo bf16 (s-local rows)
        if (wm == half) {
#pragma unroll
            for (int i = 0; i < 4; ++i) {
#pragma unroll
                for (int j = 0; j < 4; ++j) {
                    int col = wn * 64 + j * 16 + fr;
                    int g = col >> 3;
                    int cb = (col & 7) * 2;
#pragma unroll
                    for (int r = 0; r < 4; ++r) {
                        int rr = i * 16 + quad * 4 + r;
                        int gs = (g & 8) | ((g ^ rr) & 7);
                        float v = lrelu(acc[i][j][r]);
                        uint32 u = __float_as_uint(v);
                        *(unsigned short*)(smem +         rr * 256 + gs * 16 + cb) = (unsigned short)(u >> 16);
                        float lo = v - __uint_as_float(u & 0xffff0000u);
                        *(unsigned short*)(smem + 16384 + rr * 256 + gs * 16 + cb) =
                            (unsigned short)(__float_as_uint(lo) >> 16);
                    }
                }
            }
        }
        __syncthreads();

        for (int tc = 0; tc < n; tc += 32) {
            int nn = min(32, n - tc);
            // stage 32 routed query rows (128 q) as hi/lo bf16
            if (t_idx < nn) {
                int tt = tl[tc + t_idx];
                const float* qp = qv + ((size_t)tt * B_ + b) * Q_ + qoff + seg * 16;
                float4 f0 = *(const float4*)(qp);
                float4 f1 = *(const float4*)(qp + 4);
                float4 f2 = *(const float4*)(qp + 8);
                float4 f3 = *(const float4*)(qp + 12);
                uint4 h0 = make_uint4(pack_hi2(f0.x, f0.y), pack_hi2(f0.z, f0.w),
                                      pack_hi2(f1.x, f1.y), pack_hi2(f1.z, f1.w));
                uint4 h1 = make_uint4(pack_hi2(f2.x, f2.y), pack_hi2(f2.z, f2.w),
                                      pack_hi2(f3.x, f3.y), pack_hi2(f3.z, f3.w));
                uint4 l0 = make_uint4(pack_hi2(resid(f0.x), resid(f0.y)), pack_hi2(resid(f0.z), resid(f0.w)),
                                      pack_hi2(resid(f1.x), resid(f1.y)), pack_hi2(resid(f1.z), resid(f1.w)));
                uint4 l1 = make_uint4(pack_hi2(resid(f2.x), resid(f2.y)), pack_hi2(resid(f2.z), resid(f2.w)),
                                      pack_hi2(resid(f3.x), resid(f3.y)), pack_hi2(resid(f3.z), resid(f3.w)));
                int g0 = seg * 2, g1 = seg * 2 + 1;
                int gs0 = (g0 & 8) | ((g0 ^ t_idx) & 7);
                int gs1 = (g1 & 8) | ((g1 ^ t_idx) & 7);
                *(uint4*)(smem + 32768 + t_idx * 256 + gs0 * 16) = h0;
                *(uint4*)(smem + 32768 + t_idx * 256 + gs1 * 16) = h1;
                *(uint4*)(smem + 40960 + t_idx * 256 + gs0 * 16) = l0;
                *(uint4*)(smem + 40960 + t_idx * 256 + gs1 * 16) = l1;
            }
            __syncthreads();

            // score MFMA: A = qv (m=t, up to 32), B = P (n=s, wave owns 16)
            f32x4 sc0 = {0.f, 0.f, 0.f, 0.f}, sc1 = {0.f, 0.f, 0.f, 0.f};
#pragma unroll
            for (int ks = 0; ks < 4; ++ks) {
                int kb = ks * 4 + quad;
                int ko = ((kb & 8) | ((kb ^ xr) & 7)) * 16;
                int prow = wave * 16 + fr;
                bf16x8 ph = *(const bf16x8*)(smem +         prow * 256 + ko);
                bf16x8 pl = *(const bf16x8*)(smem + 16384 + prow * 256 + ko);
                bf16x8 qh0 = *(const bf16x8*)(smem + 32768 + fr * 256 + ko);
                bf16x8 ql0 = *(const bf16x8*)(smem + 40960 + fr * 256 + ko);
                sc0 = __builtin_amdgcn_mfma_f32_16x16x32_bf16(qh0, ph, sc0, 0, 0, 0);
                sc0 = __builtin_amdgcn_mfma_f32_16x16x32_bf16(qh0, pl, sc0, 0, 0, 0);
                sc0 = __builtin_amdgcn_mfma_f32_16x16x32_bf16(ql0, ph, sc0, 0, 0, 0);
                if (nn > 16) {
                    bf16x8 qh1 = *(const bf16x8*)(smem + 32768 + (16 + fr) * 256 + ko);
                    bf16x8 ql1 = *(const bf16x8*)(smem + 40960 + (16 + fr) * 256 + ko);
                    sc1 = __builtin_amdgcn_mfma_f32_16x16x32_bf16(qh1, ph, sc1, 0, 0, 0);
                    sc1 = __builtin_amdgcn_mfma_f32_16x16x32_bf16(qh1, pl, sc1, 0, 0, 0);
                    sc1 = __builtin_amdgcn_mfma_f32_16x16x32_bf16(ql1, ph, sc1, 0, 0, 0);
                }
            }
            // D rows = t (quad*4+r per 16-tile), cols = s (fr)
            int sg = sbase + half * 64 + wave * 16 + fr;
#pragma unroll
            for (int r = 0; r < 4; ++r) {
                int t0 = quad * 4 + r;
                if (t0 < nn) {
                    int tg = tl[tc + t0];
                    atomicAdd(out + ((size_t)tg * B_ + b) * S_ + sg, sc0[r]);
                }
                int t1 = 16 + quad * 4 + r;
                if (t1 < nn) {
                    int tg = tl[tc + t1];
                    atomicAdd(out + ((size_t)tg * B_ + b) * S_ + sg, sc1[r]);
                }
            }
            __syncthreads();
        }
        __syncthreads();   // all score reads done before next half's P write
    }
}

// ---------------------------------------------------------------------------
// Masked softmax over S per (t,b) row, in place.
// ---------------------------------------------------------------------------
__global__ __launch_bounds__(256) void softmax_kernel(
    float* __restrict__ out, const int* __restrict__ mask) {
    const int row = blockIdx.x;
    const int b = row & (B_ - 1);
    float* w = out + (size_t)row * S_;
    const int* mrow = mask + (size_t)b * S_;
    const int tid = threadIdx.x;

    float4 v = *(const float4*)(w + tid * 4);
    int4 mm = *(const int4*)(mrow + tid * 4);
    float x0 = mm.x ? -INFINITY : v.x;
    float x1 = mm.y ? -INFINITY : v.y;
    float x2 = mm.z ? -INFINITY : v.z;
    float x3 = mm.w ? -INFINITY : v.w;

    float lmax = fmaxf(fmaxf(x0, x1), fmaxf(x2, x3));
#pragma unroll
    for (int off = 32; off >= 1; off >>= 1)
        lmax = fmaxf(lmax, __shfl_down(lmax, off));

    __shared__ float redmax[4];
    __shared__ float redsum[4];
    const int wave = tid >> 6, lane = tid & 63;
    if (lane == 0) redmax[wave] = lmax;
    __syncthreads();
    float gmax = fmaxf(fmaxf(redmax[0], redmax[1]), fmaxf(redmax[2], redmax[3]));

    float e0 = mm.x ? 0.f : __expf(x0 - gmax);
    float e1 = mm.y ? 0.f : __expf(x1 - gmax);
    float e2 = mm.z ? 0.f : __expf(x2 - gmax);
    float e3 = mm.w ? 0.f : __expf(x3 - gmax);
    float lsum = e0 + e1 + e2 + e3;
#pragma unroll
    for (int off = 32; off >= 1; off >>= 1)
        lsum += __shfl_down(lsum, off);
    if (lane == 0) redsum[wave] = lsum;
    __syncthreads();
    float gsum = redsum[0] + redsum[1] + redsum[2] + redsum[3];
    float rinv = 1.0f / gsum;

    *(float4*)(w + tid * 4) = make_float4(e0 * rinv, e1 * rinv, e2 * rinv, e3 * rinv);
}

// ---------------------------------------------------------------------------
extern "C" void kernel_launch(void* const* d_in, const int* in_sizes, int n_in,
                              void* d_out, int out_size, void* d_ws, size_t ws_size,
                              hipStream_t stream) {
    float* src  = (float*)d_in[0];               // (B,S,E) — repacked in-place
    const int* mask = (const int*)d_in[1];       // (B,S)
    const float* qv = (const float*)d_in[2];     // (T,B,Q) fp32 (NOT repacked)
    float* Wsrc = (float*)d_in[3];               // (H*Q,E) — repacked in-place
    const float* Wopt = (const float*)d_in[4];   // (H,Q)
    float* out = (float*)d_out;                  // (T,B,S)

    int* cnt = (int*)d_ws;
    int* lists = cnt + 256;

    hipMemsetAsync(cnt, 0, 128 * sizeof(int), stream);
    hipMemsetAsync(d_out, 0, (size_t)out_size * sizeof(float), stream);

    hipLaunchKernelGGL(repack_kernel, dim3((M_ * 8 + 255) / 256), dim3(256), 0, stream,
                       src, M_ * 8);
    hipLaunchKernelGGL(repack_kernel, dim3((F_ * 8 + 255) / 256), dim3(256), 0, stream,
                       Wsrc, F_ * 8);
    hipLaunchKernelGGL(head_select_kernel, dim3(T_ * B_ / 4), dim3(256), 0, stream,
                       qv, Wopt, cnt, lists);
    hipLaunchKernelGGL(proj_score_kernel, dim3(F_ / 128, M_ / 128), dim3(256), 0, stream,
                       (const unsigned char*)src, (const unsigned char*)Wsrc,
                       qv, cnt, lists, out);
    hipLaunchKernelGGL(softmax_kernel, dim3(T_ * B_), dim3(256), 0, stream,
                       out, mask);
}

// Round 4
// 259.115 us; speedup vs baseline: 2.2191x; 1.0680x over previous
//
#include <hip/hip_runtime.h>
#include <hip/hip_bf16.h>
#include <math.h>

#define B_ 32
#define S_ 1024
#define E_ 512
#define T_ 128
#define Q_ 256
#define H_ 4
#define F_ (H_ * Q_)      // 1024
#define M_ (B_ * S_)      // 32768

typedef __bf16 bf16x8 __attribute__((ext_vector_type(8)));
typedef float f32x4 __attribute__((ext_vector_type(4)));
typedef unsigned int uint32;

__device__ __forceinline__ float lrelu(float x) { return x > 0.0f ? x : 0.01f * x; }
__device__ __forceinline__ uint32 pack_hi2(float a, float b) {
    return (__float_as_uint(a) >> 16) | (__float_as_uint(b) & 0xffff0000u);
}
__device__ __forceinline__ float resid(float f) {
    return f - __uint_as_float(__float_as_uint(f) & 0xffff0000u);
}

#define GLOAD_LDS16(g, l)                                                       \
    __builtin_amdgcn_global_load_lds(                                           \
        (const __attribute__((address_space(1))) void*)(g),                     \
        (__attribute__((address_space(3))) void*)(l), 16, 0, 0)

// ---------------------------------------------------------------------------
// In-place hi/lo bf16 repack, coalesced: 16 threads per 64-float window.
// Thread j of window c: loads float4 at [c*64 + j*4] (lane-contiguous),
// stores 8B hi at byte j*8 and 8B lo at byte 128+j*8 of the window.
// Window is contained in one wave; store data depends on loads, so the
// compiler's s_waitcnt drains all lanes' loads before any store issues.
// Blocks [0,16384) cover src (262144 windows); [16384,16896) cover W_src.
// ---------------------------------------------------------------------------
#define SRC_BLOCKS 16384
__global__ __launch_bounds__(256) void repack_kernel(float* src, float* wsrc) {
    const int blk = blockIdx.x;
    float* base = (blk < SRC_BLOCKS) ? src : wsrc;
    const size_t woff = (size_t)((blk < SRC_BLOCKS) ? blk : (blk - SRC_BLOCKS)) * 16;
    const int tid = threadIdx.x;
    const size_t c = woff + (tid >> 4);   // window index
    const int j = tid & 15;
    float* wp = base + c * 64;
    float4 v = *(const float4*)(wp + j * 4);
    uint32 h0 = pack_hi2(v.x, v.y), h1 = pack_hi2(v.z, v.w);
    uint32 l0 = pack_hi2(resid(v.x), resid(v.y));
    uint32 l1 = pack_hi2(resid(v.z), resid(v.w));
    *(uint2*)((char*)wp + j * 8)       = make_uint2(h0, h1);
    *(uint2*)((char*)wp + 128 + j * 8) = make_uint2(l0, l1);
}

// ---------------------------------------------------------------------------
// Head routing: one wave per (t,b). Shuffle-reduce 4 head dots, argmax, route.
// ---------------------------------------------------------------------------
__global__ __launch_bounds__(256) void head_select_kernel(
    const float* __restrict__ qv, const float* __restrict__ Wopt,
    int* __restrict__ cnt, int* __restrict__ lists) {
    const int wave = threadIdx.x >> 6, lane = threadIdx.x & 63;
    const int idx = blockIdx.x * 4 + wave;       // t*B + b, grid = 1024
    const int t = idx >> 5, b = idx & (B_ - 1);
    const float4 qq = *(const float4*)(qv + (size_t)idx * Q_ + lane * 4);
    float s[4];
#pragma unroll
    for (int h = 0; h < 4; ++h) {
        float4 w = *(const float4*)(Wopt + h * Q_ + lane * 4);
        s[h] = qq.x * w.x + qq.y * w.y + qq.z * w.z + qq.w * w.w;
    }
#pragma unroll
    for (int off = 32; off >= 1; off >>= 1) {
#pragma unroll
        for (int h = 0; h < 4; ++h) s[h] += __shfl_down(s[h], off);
    }
    if (lane == 0) {
        int bh = 0; float bs = s[0];
        if (s[1] > bs) { bs = s[1]; bh = 1; }
        if (s[2] > bs) { bs = s[2]; bh = 2; }
        if (s[3] > bs) { bs = s[3]; bh = 3; }
        int slot = atomicAdd(&cnt[b * H_ + bh], 1);
        lists[(b * H_ + bh) * T_ + slot] = t;
    }
}

// ---------------------------------------------------------------------------
// Fused proj+score (unchanged from round 3 — at the m97 structural plateau).
// ---------------------------------------------------------------------------
__global__ __launch_bounds__(256, 2) void proj_score_kernel(
    const unsigned char* __restrict__ Apk,   // repacked src
    const unsigned char* __restrict__ Wpk,   // repacked W_src
    const float* __restrict__ qv,            // (T,B,Q) fp32
    const int* __restrict__ cnt,
    const int* __restrict__ lists,
    float* __restrict__ out)                 // (T,B,S), pre-zeroed
{
    __shared__ uint4 smem4[4096];            // 64 KB, carved below
    char* smem = (char*)smem4;
    // K-loop:   Ah [0,16K) Al [16K,32K) Bh [32K,48K) Bl [48K,64K)
    // Epilogue: Ph [0,16K) Pl [16K,32K) Qh [32K,40K) Ql [40K,48K) tl [48K,+512)

    const int bj = blockIdx.x;   // 0..7
    const int bi = blockIdx.y;   // 0..255
    const int tid = threadIdx.x;
    const int wave = tid >> 6, lane = tid & 63;
    const int wm = wave >> 1, wn = wave & 1;
    const int quad = lane >> 4;
    const int fr = lane & 15;
    const int xr = fr & 7;

    const int srow = lane >> 3;                       // row-in-chunk 0..7
    const int sgg = ((lane & 7) ^ srow) * 16;         // swizzled source granule

    const size_t Abase = (size_t)(bi * 128) * 2048;
    const size_t Wbase = (size_t)(bj * 128) * 2048;

    const int ko0 = ((quad ^ xr) & 7) * 16;
    const int ko1 = (((quad ^ 4) ^ xr) & 7) * 16;

    f32x4 acc[4][4] = {};

    for (int kc = 0; kc < 8; ++kc) {
        const size_t koff = (size_t)kc * 256;
        __syncthreads();
#pragma unroll
        for (int c = 0; c < 4; ++c) {
            int chunk = wave * 4 + c;                 // 0..15 (8 rows each)
            int row = chunk * 8 + srow;
            const unsigned char* ga = Apk + Abase + (size_t)row * 2048 + koff + sgg;
            const unsigned char* gw = Wpk + Wbase + (size_t)row * 2048 + koff + sgg;
            GLOAD_LDS16(ga,       smem +     chunk * 1024);
            GLOAD_LDS16(ga + 128, smem + 16384 + chunk * 1024);
            GLOAD_LDS16(gw,       smem + 32768 + chunk * 1024);
            GLOAD_LDS16(gw + 128, smem + 49152 + chunk * 1024);
        }
        __syncthreads();
#pragma unroll
        for (int kk = 0; kk < 2; ++kk) {
            const int ko = kk ? ko1 : ko0;
            bf16x8 ah[4], al[4], bh[4], bl[4];
#pragma unroll
            for (int i = 0; i < 4; ++i) {
                int ra = wm * 64 + i * 16 + fr;
                int rb = wn * 64 + i * 16 + fr;
                ah[i] = *(const bf16x8*)(smem +         ra * 128 + ko);
                al[i] = *(const bf16x8*)(smem + 16384 + ra * 128 + ko);
                bh[i] = *(const bf16x8*)(smem + 32768 + rb * 128 + ko);
                bl[i] = *(const bf16x8*)(smem + 49152 + rb * 128 + ko);
            }
#pragma unroll
            for (int i = 0; i < 4; ++i)
#pragma unroll
                for (int j = 0; j < 4; ++j) {
                    acc[i][j] = __builtin_amdgcn_mfma_f32_16x16x32_bf16(ah[i], bh[j], acc[i][j], 0, 0, 0);
                    acc[i][j] = __builtin_amdgcn_mfma_f32_16x16x32_bf16(ah[i], bl[j], acc[i][j], 0, 0, 0);
                    acc[i][j] = __builtin_amdgcn_mfma_f32_16x16x32_bf16(al[i], bh[j], acc[i][j], 0, 0, 0);
                }
        }
    }

    // ---- fused score epilogue ----
    const int b = bi >> 3;
    const int sbase = (bi & 7) * 128;
    const int h = bj >> 1;
    const int qoff = (bj & 1) * 128;
    const int bh_idx = b * H_ + h;
    const int n = cnt[bh_idx];

    __syncthreads();
    int* tl = (int*)(smem + 49152);
    if (tid < 128) tl[tid] = lists[bh_idx * T_ + tid];

    const int t_idx = tid >> 3, seg = tid & 7;

    for (int half = 0; half < 2; ++half) {
        if (wm == half) {
#pragma unroll
            for (int i = 0; i < 4; ++i) {
#pragma unroll
                for (int j = 0; j < 4; ++j) {
                    int col = wn * 64 + j * 16 + fr;
                    int g = col >> 3;
                    int cb = (col & 7) * 2;
#pragma unroll
                    for (int r = 0; r < 4; ++r) {
                        int rr = i * 16 + quad * 4 + r;
                        int gs = (g & 8) | ((g ^ rr) & 7);
                        float v = lrelu(acc[i][j][r]);
                        uint32 u = __float_as_uint(v);
                        *(unsigned short*)(smem +         rr * 256 + gs * 16 + cb) = (unsigned short)(u >> 16);
                        float lo = v - __uint_as_float(u & 0xffff0000u);
                        *(unsigned short*)(smem + 16384 + rr * 256 + gs * 16 + cb) =
                            (unsigned short)(__float_as_uint(lo) >> 16);
                    }
                }
            }
        }
        __syncthreads();

        for (int tc = 0; tc < n; tc += 32) {
            int nn = min(32, n - tc);
            if (t_idx < nn) {
                int tt = tl[tc + t_idx];
                const float* qp = qv + ((size_t)tt * B_ + b) * Q_ + qoff + seg * 16;
                float4 f0 = *(const float4*)(qp);
                float4 f1 = *(const float4*)(qp + 4);
                float4 f2 = *(const float4*)(qp + 8);
                float4 f3 = *(const float4*)(qp + 12);
                uint4 h0 = make_uint4(pack_hi2(f0.x, f0.y), pack_hi2(f0.z, f0.w),
                                      pack_hi2(f1.x, f1.y), pack_hi2(f1.z, f1.w));
                uint4 h1 = make_uint4(pack_hi2(f2.x, f2.y), pack_hi2(f2.z, f2.w),
                                      pack_hi2(f3.x, f3.y), pack_hi2(f3.z, f3.w));
                uint4 l0 = make_uint4(pack_hi2(resid(f0.x), resid(f0.y)), pack_hi2(resid(f0.z), resid(f0.w)),
                                      pack_hi2(resid(f1.x), resid(f1.y)), pack_hi2(resid(f1.z), resid(f1.w)));
                uint4 l1 = make_uint4(pack_hi2(resid(f2.x), resid(f2.y)), pack_hi2(resid(f2.z), resid(f2.w)),
                                      pack_hi2(resid(f3.x), resid(f3.y)), pack_hi2(resid(f3.z), resid(f3.w)));
                int g0 = seg * 2, g1 = seg * 2 + 1;
                int gs0 = (g0 & 8) | ((g0 ^ t_idx) & 7);
                int gs1 = (g1 & 8) | ((g1 ^ t_idx) & 7);
                *(uint4*)(smem + 32768 + t_idx * 256 + gs0 * 16) = h0;
                *(uint4*)(smem + 32768 + t_idx * 256 + gs1 * 16) = h1;
                *(uint4*)(smem + 40960 + t_idx * 256 + gs0 * 16) = l0;
                *(uint4*)(smem + 40960 + t_idx * 256 + gs1 * 16) = l1;
            }
            __syncthreads();

            f32x4 sc0 = {0.f, 0.f, 0.f, 0.f}, sc1 = {0.f, 0.f, 0.f, 0.f};
#pragma unroll
            for (int ks = 0; ks < 4; ++ks) {
                int kb = ks * 4 + quad;
                int ko = ((kb & 8) | ((kb ^ xr) & 7)) * 16;
                int prow = wave * 16 + fr;
                bf16x8 ph = *(const bf16x8*)(smem +         prow * 256 + ko);
                bf16x8 pl = *(const bf16x8*)(smem + 16384 + prow * 256 + ko);
                bf16x8 qh0 = *(const bf16x8*)(smem + 32768 + fr * 256 + ko);
                bf16x8 ql0 = *(const bf16x8*)(smem + 40960 + fr * 256 + ko);
                sc0 = __builtin_amdgcn_mfma_f32_16x16x32_bf16(qh0, ph, sc0, 0, 0, 0);
                sc0 = __builtin_amdgcn_mfma_f32_16x16x32_bf16(qh0, pl, sc0, 0, 0, 0);
                sc0 = __builtin_amdgcn_mfma_f32_16x16x32_bf16(ql0, ph, sc0, 0, 0, 0);
                if (nn > 16) {
                    bf16x8 qh1 = *(const bf16x8*)(smem + 32768 + (16 + fr) * 256 + ko);
                    bf16x8 ql1 = *(const bf16x8*)(smem + 40960 + (16 + fr) * 256 + ko);
                    sc1 = __builtin_amdgcn_mfma_f32_16x16x32_bf16(qh1, ph, sc1, 0, 0, 0);
                    sc1 = __builtin_amdgcn_mfma_f32_16x16x32_bf16(qh1, pl, sc1, 0, 0, 0);
                    sc1 = __builtin_amdgcn_mfma_f32_16x16x32_bf16(ql1, ph, sc1, 0, 0, 0);
                }
            }
            int sg = sbase + half * 64 + wave * 16 + fr;
#pragma unroll
            for (int r = 0; r < 4; ++r) {
                int t0 = quad * 4 + r;
                if (t0 < nn) {
                    int tg = tl[tc + t0];
                    atomicAdd(out + ((size_t)tg * B_ + b) * S_ + sg, sc0[r]);
                }
                int t1 = 16 + quad * 4 + r;
                if (t1 < nn) {
                    int tg = tl[tc + t1];
                    atomicAdd(out + ((size_t)tg * B_ + b) * S_ + sg, sc1[r]);
                }
            }
            __syncthreads();
        }
        __syncthreads();
    }
}

// ---------------------------------------------------------------------------
// Masked softmax over S per (t,b) row, in place.
// ---------------------------------------------------------------------------
__global__ __launch_bounds__(256) void softmax_kernel(
    float* __restrict__ out, const int* __restrict__ mask) {
    const int row = blockIdx.x;
    const int b = row & (B_ - 1);
    float* w = out + (size_t)row * S_;
    const int* mrow = mask + (size_t)b * S_;
    const int tid = threadIdx.x;

    float4 v = *(const float4*)(w + tid * 4);
    int4 mm = *(const int4*)(mrow + tid * 4);
    float x0 = mm.x ? -INFINITY : v.x;
    float x1 = mm.y ? -INFINITY : v.y;
    float x2 = mm.z ? -INFINITY : v.z;
    float x3 = mm.w ? -INFINITY : v.w;

    float lmax = fmaxf(fmaxf(x0, x1), fmaxf(x2, x3));
#pragma unroll
    for (int off = 32; off >= 1; off >>= 1)
        lmax = fmaxf(lmax, __shfl_down(lmax, off));

    __shared__ float redmax[4];
    __shared__ float redsum[4];
    const int wave = tid >> 6, lane = tid & 63;
    if (lane == 0) redmax[wave] = lmax;
    __syncthreads();
    float gmax = fmaxf(fmaxf(redmax[0], redmax[1]), fmaxf(redmax[2], redmax[3]));

    float e0 = mm.x ? 0.f : __expf(x0 - gmax);
    float e1 = mm.y ? 0.f : __expf(x1 - gmax);
    float e2 = mm.z ? 0.f : __expf(x2 - gmax);
    float e3 = mm.w ? 0.f : __expf(x3 - gmax);
    float lsum = e0 + e1 + e2 + e3;
#pragma unroll
    for (int off = 32; off >= 1; off >>= 1)
        lsum += __shfl_down(lsum, off);
    if (lane == 0) redsum[wave] = lsum;
    __syncthreads();
    float gsum = redsum[0] + redsum[1] + redsum[2] + redsum[3];
    float rinv = 1.0f / gsum;

    *(float4*)(w + tid * 4) = make_float4(e0 * rinv, e1 * rinv, e2 * rinv, e3 * rinv);
}

// ---------------------------------------------------------------------------
extern "C" void kernel_launch(void* const* d_in, const int* in_sizes, int n_in,
                              void* d_out, int out_size, void* d_ws, size_t ws_size,
                              hipStream_t stream) {
    float* src  = (float*)d_in[0];               // (B,S,E) — repacked in-place
    const int* mask = (const int*)d_in[1];       // (B,S)
    const float* qv = (const float*)d_in[2];     // (T,B,Q) fp32 (NOT repacked)
    float* Wsrc = (float*)d_in[3];               // (H*Q,E) — repacked in-place
    const float* Wopt = (const float*)d_in[4];   // (H,Q)
    float* out = (float*)d_out;                  // (T,B,S)

    int* cnt = (int*)d_ws;
    int* lists = cnt + 256;

    hipMemsetAsync(cnt, 0, 128 * sizeof(int), stream);
    hipMemsetAsync(d_out, 0, (size_t)out_size * sizeof(float), stream);

    hipLaunchKernelGGL(repack_kernel, dim3(SRC_BLOCKS + F_ * E_ / 64 / 16), dim3(256), 0, stream,
                       src, Wsrc);
    hipLaunchKernelGGL(head_select_kernel, dim3(T_ * B_ / 4), dim3(256), 0, stream,
                       qv, Wopt, cnt, lists);
    hipLaunchKernelGGL(proj_score_kernel, dim3(F_ / 128, M_ / 128), dim3(256), 0, stream,
                       (const unsigned char*)src, (const unsigned char*)Wsrc,
                       qv, cnt, lists, out);
    hipLaunchKernelGGL(softmax_kernel, dim3(T_ * B_), dim3(256), 0, stream,
                       out, mask);
}

// Round 5
// 240.729 us; speedup vs baseline: 2.3886x; 1.0764x over previous
//
#include <hip/hip_runtime.h>
#include <hip/hip_bf16.h>
#include <math.h>

#define B_ 32
#define S_ 1024
#define E_ 512
#define T_ 128
#define Q_ 256
#define H_ 4
#define F_ (H_ * Q_)      // 1024
#define M_ (B_ * S_)      // 32768

typedef __bf16 bf16x8 __attribute__((ext_vector_type(8)));
typedef float f32x4 __attribute__((ext_vector_type(4)));
typedef unsigned int uint32;

__device__ __forceinline__ float lrelu(float x) { return x > 0.0f ? x : 0.01f * x; }
__device__ __forceinline__ uint32 pack_hi2(float a, float b) {
    return (__float_as_uint(a) >> 16) | (__float_as_uint(b) & 0xffff0000u);
}
__device__ __forceinline__ float resid(float f) {
    return f - __uint_as_float(__float_as_uint(f) & 0xffff0000u);
}

#define GLOAD_LDS16(g, l)                                                       \
    __builtin_amdgcn_global_load_lds(                                           \
        (const __attribute__((address_space(1))) void*)(g),                     \
        (__attribute__((address_space(3))) void*)(l), 16, 0, 0)

#define SRC_BLOCKS 16384      // src windows / 16
#define W_BLOCKS   512        // W_src windows / 16
#define HS_BLOCKS  1024       // head-select: wave per (t,b), 4 waves/block

// ---------------------------------------------------------------------------
// Fused prep: blocks [0, SRC_BLOCKS+W_BLOCKS) repack src/W_src in place
// (hi/lo bf16 per 64-float window); blocks beyond that compute the per-(t,b)
// argmax head into best[] (dense, no atomics).
// ---------------------------------------------------------------------------
__global__ __launch_bounds__(256) void prep_kernel(
    float* src, float* wsrc,
    const float* __restrict__ qv, const float* __restrict__ Wopt,
    int* __restrict__ best) {
    const int blk = blockIdx.x;
    if (blk < SRC_BLOCKS + W_BLOCKS) {
        float* base = (blk < SRC_BLOCKS) ? src : wsrc;
        const size_t woff = (size_t)((blk < SRC_BLOCKS) ? blk : (blk - SRC_BLOCKS)) * 16;
        const int tid = threadIdx.x;
        const size_t c = woff + (tid >> 4);
        const int j = tid & 15;
        float* wp = base + c * 64;
        float4 v = *(const float4*)(wp + j * 4);
        uint32 h0 = pack_hi2(v.x, v.y), h1 = pack_hi2(v.z, v.w);
        uint32 l0 = pack_hi2(resid(v.x), resid(v.y));
        uint32 l1 = pack_hi2(resid(v.z), resid(v.w));
        *(uint2*)((char*)wp + j * 8)       = make_uint2(h0, h1);
        *(uint2*)((char*)wp + 128 + j * 8) = make_uint2(l0, l1);
    } else {
        const int wave = threadIdx.x >> 6, lane = threadIdx.x & 63;
        const int idx = (blk - SRC_BLOCKS - W_BLOCKS) * 4 + wave;   // t*B + b
        const float4 qq = *(const float4*)(qv + (size_t)idx * Q_ + lane * 4);
        float s[4];
#pragma unroll
        for (int h = 0; h < 4; ++h) {
            float4 w = *(const float4*)(Wopt + h * Q_ + lane * 4);
            s[h] = qq.x * w.x + qq.y * w.y + qq.z * w.z + qq.w * w.w;
        }
#pragma unroll
        for (int off = 32; off >= 1; off >>= 1) {
#pragma unroll
            for (int h = 0; h < 4; ++h) s[h] += __shfl_down(s[h], off);
        }
        if (lane == 0) {
            int bh = 0; float bs = s[0];
            if (s[1] > bs) { bs = s[1]; bh = 1; }
            if (s[2] > bs) { bs = s[2]; bh = 2; }
            if (s[3] > bs) { bs = s[3]; bh = 3; }
            best[idx] = bh;
        }
    }
}

// ---------------------------------------------------------------------------
// Fused proj+score. K-loop unchanged (split-bf16 3-MFMA, XOR-swizzled LDS).
// Epilogue: builds the (b,h) t-list locally from best[], scores via split
// MFMA, and writes PLAIN stores into per-q-half buffers (no atomics, no
// pre-zero needed — every element of each buffer written exactly once).
// ---------------------------------------------------------------------------
__global__ __launch_bounds__(256, 2) void proj_score_kernel(
    const unsigned char* __restrict__ Apk,   // repacked src
    const unsigned char* __restrict__ Wpk,   // repacked W_src
    const float* __restrict__ qv,            // (T,B,Q) fp32
    const int* __restrict__ best,            // (T*B)
    float* __restrict__ bufs)                // 2 x (T,B,S) in ws
{
    __shared__ uint4 smem4[4096];            // 64 KB
    char* smem = (char*)smem4;
    // K-loop:   Ah [0,16K) Al [16K,32K) Bh [32K,48K) Bl [48K,64K)
    // Epilogue: Ph [0,16K) Pl [16K,32K) Qh [32K,40K) Ql [40K,48K)
    //           tl [48K,48K+512) lcnt @48K+512

    const int bj = blockIdx.x;   // 0..7
    const int bi = blockIdx.y;   // 0..255
    const int tid = threadIdx.x;
    const int wave = tid >> 6, lane = tid & 63;
    const int wm = wave >> 1, wn = wave & 1;
    const int quad = lane >> 4;
    const int fr = lane & 15;
    const int xr = fr & 7;

    const int srow = lane >> 3;
    const int sgg = ((lane & 7) ^ srow) * 16;

    const size_t Abase = (size_t)(bi * 128) * 2048;
    const size_t Wbase = (size_t)(bj * 128) * 2048;

    const int ko0 = ((quad ^ xr) & 7) * 16;
    const int ko1 = (((quad ^ 4) ^ xr) & 7) * 16;

    f32x4 acc[4][4] = {};

    for (int kc = 0; kc < 8; ++kc) {
        const size_t koff = (size_t)kc * 256;
        __syncthreads();
#pragma unroll
        for (int c = 0; c < 4; ++c) {
            int chunk = wave * 4 + c;
            int row = chunk * 8 + srow;
            const unsigned char* ga = Apk + Abase + (size_t)row * 2048 + koff + sgg;
            const unsigned char* gw = Wpk + Wbase + (size_t)row * 2048 + koff + sgg;
            GLOAD_LDS16(ga,       smem +     chunk * 1024);
            GLOAD_LDS16(ga + 128, smem + 16384 + chunk * 1024);
            GLOAD_LDS16(gw,       smem + 32768 + chunk * 1024);
            GLOAD_LDS16(gw + 128, smem + 49152 + chunk * 1024);
        }
        __syncthreads();
#pragma unroll
        for (int kk = 0; kk < 2; ++kk) {
            const int ko = kk ? ko1 : ko0;
            bf16x8 ah[4], al[4], bh[4], bl[4];
#pragma unroll
            for (int i = 0; i < 4; ++i) {
                int ra = wm * 64 + i * 16 + fr;
                int rb = wn * 64 + i * 16 + fr;
                ah[i] = *(const bf16x8*)(smem +         ra * 128 + ko);
                al[i] = *(const bf16x8*)(smem + 16384 + ra * 128 + ko);
                bh[i] = *(const bf16x8*)(smem + 32768 + rb * 128 + ko);
                bl[i] = *(const bf16x8*)(smem + 49152 + rb * 128 + ko);
            }
#pragma unroll
            for (int i = 0; i < 4; ++i)
#pragma unroll
                for (int j = 0; j < 4; ++j) {
                    acc[i][j] = __builtin_amdgcn_mfma_f32_16x16x32_bf16(ah[i], bh[j], acc[i][j], 0, 0, 0);
                    acc[i][j] = __builtin_amdgcn_mfma_f32_16x16x32_bf16(ah[i], bl[j], acc[i][j], 0, 0, 0);
                    acc[i][j] = __builtin_amdgcn_mfma_f32_16x16x32_bf16(al[i], bh[j], acc[i][j], 0, 0, 0);
                }
        }
    }

    // ---- fused score epilogue ----
    const int b = bi >> 3;
    const int sbase = (bi & 7) * 128;
    const int h = bj >> 1;
    const int qoff = (bj & 1) * 128;
    float* buf = bufs + (size_t)(bj & 1) * ((size_t)T_ * B_ * S_);

    __syncthreads();                       // K-loop LDS reads done
    int* tl = (int*)(smem + 49152);
    int* lcnt = (int*)(smem + 49152 + 512);
    if (tid == 0) *lcnt = 0;
    __syncthreads();
    if (tid < 128) {
        if (best[tid * B_ + b] == h) {
            int slot = atomicAdd(lcnt, 1);   // LDS atomic
            tl[slot] = tid;
        }
    }
    __syncthreads();
    const int n = *lcnt;

    const int t_idx = tid >> 3, seg = tid & 7;

    for (int half = 0; half < 2; ++half) {
        if (wm == half) {
#pragma unroll
            for (int i = 0; i < 4; ++i) {
#pragma unroll
                for (int j = 0; j < 4; ++j) {
                    int col = wn * 64 + j * 16 + fr;
                    int g = col >> 3;
                    int cb = (col & 7) * 2;
#pragma unroll
                    for (int r = 0; r < 4; ++r) {
                        int rr = i * 16 + quad * 4 + r;
                        int gs = (g & 8) | ((g ^ rr) & 7);
                        float v = lrelu(acc[i][j][r]);
                        uint32 u = __float_as_uint(v);
                        *(unsigned short*)(smem +         rr * 256 + gs * 16 + cb) = (unsigned short)(u >> 16);
                        float lo = v - __uint_as_float(u & 0xffff0000u);
                        *(unsigned short*)(smem + 16384 + rr * 256 + gs * 16 + cb) =
                            (unsigned short)(__float_as_uint(lo) >> 16);
                    }
                }
            }
        }
        __syncthreads();

        for (int tc = 0; tc < n; tc += 32) {
            int nn = min(32, n - tc);
            if (t_idx < nn) {
                int tt = tl[tc + t_idx];
                const float* qp = qv + ((size_t)tt * B_ + b) * Q_ + qoff + seg * 16;
                float4 f0 = *(const float4*)(qp);
                float4 f1 = *(const float4*)(qp + 4);
                float4 f2 = *(const float4*)(qp + 8);
                float4 f3 = *(const float4*)(qp + 12);
                uint4 h0 = make_uint4(pack_hi2(f0.x, f0.y), pack_hi2(f0.z, f0.w),
                                      pack_hi2(f1.x, f1.y), pack_hi2(f1.z, f1.w));
                uint4 h1 = make_uint4(pack_hi2(f2.x, f2.y), pack_hi2(f2.z, f2.w),
                                      pack_hi2(f3.x, f3.y), pack_hi2(f3.z, f3.w));
                uint4 l0 = make_uint4(pack_hi2(resid(f0.x), resid(f0.y)), pack_hi2(resid(f0.z), resid(f0.w)),
                                      pack_hi2(resid(f1.x), resid(f1.y)), pack_hi2(resid(f1.z), resid(f1.w)));
                uint4 l1 = make_uint4(pack_hi2(resid(f2.x), resid(f2.y)), pack_hi2(resid(f2.z), resid(f2.w)),
                                      pack_hi2(resid(f3.x), resid(f3.y)), pack_hi2(resid(f3.z), resid(f3.w)));
                int g0 = seg * 2, g1 = seg * 2 + 1;
                int gs0 = (g0 & 8) | ((g0 ^ t_idx) & 7);
                int gs1 = (g1 & 8) | ((g1 ^ t_idx) & 7);
                *(uint4*)(smem + 32768 + t_idx * 256 + gs0 * 16) = h0;
                *(uint4*)(smem + 32768 + t_idx * 256 + gs1 * 16) = h1;
                *(uint4*)(smem + 40960 + t_idx * 256 + gs0 * 16) = l0;
                *(uint4*)(smem + 40960 + t_idx * 256 + gs1 * 16) = l1;
            }
            __syncthreads();

            f32x4 sc0 = {0.f, 0.f, 0.f, 0.f}, sc1 = {0.f, 0.f, 0.f, 0.f};
#pragma unroll
            for (int ks = 0; ks < 4; ++ks) {
                int kb = ks * 4 + quad;
                int ko = ((kb & 8) | ((kb ^ xr) & 7)) * 16;
                int prow = wave * 16 + fr;
                bf16x8 ph = *(const bf16x8*)(smem +         prow * 256 + ko);
                bf16x8 pl = *(const bf16x8*)(smem + 16384 + prow * 256 + ko);
                bf16x8 qh0 = *(const bf16x8*)(smem + 32768 + fr * 256 + ko);
                bf16x8 ql0 = *(const bf16x8*)(smem + 40960 + fr * 256 + ko);
                sc0 = __builtin_amdgcn_mfma_f32_16x16x32_bf16(qh0, ph, sc0, 0, 0, 0);
                sc0 = __builtin_amdgcn_mfma_f32_16x16x32_bf16(qh0, pl, sc0, 0, 0, 0);
                sc0 = __builtin_amdgcn_mfma_f32_16x16x32_bf16(ql0, ph, sc0, 0, 0, 0);
                if (nn > 16) {
                    bf16x8 qh1 = *(const bf16x8*)(smem + 32768 + (16 + fr) * 256 + ko);
                    bf16x8 ql1 = *(const bf16x8*)(smem + 40960 + (16 + fr) * 256 + ko);
                    sc1 = __builtin_amdgcn_mfma_f32_16x16x32_bf16(qh1, ph, sc1, 0, 0, 0);
                    sc1 = __builtin_amdgcn_mfma_f32_16x16x32_bf16(qh1, pl, sc1, 0, 0, 0);
                    sc1 = __builtin_amdgcn_mfma_f32_16x16x32_bf16(ql1, ph, sc1, 0, 0, 0);
                }
            }
            int sg = sbase + half * 64 + wave * 16 + fr;
#pragma unroll
            for (int r = 0; r < 4; ++r) {
                int t0 = quad * 4 + r;
                if (t0 < nn) {
                    int tg = tl[tc + t0];
                    buf[((size_t)tg * B_ + b) * S_ + sg] = sc0[r];
                }
                int t1 = 16 + quad * 4 + r;
                if (t1 < nn) {
                    int tg = tl[tc + t1];
                    buf[((size_t)tg * B_ + b) * S_ + sg] = sc1[r];
                }
            }
            __syncthreads();
        }
        __syncthreads();
    }
}

// ---------------------------------------------------------------------------
// Masked softmax: logits = buf0 + buf1 (q-half partial sums), masked, softmax
// over S, write to d_out.
// ---------------------------------------------------------------------------
__global__ __launch_bounds__(256) void softmax_kernel(
    const float* __restrict__ bufs, float* __restrict__ out,
    const int* __restrict__ mask) {
    const int row = blockIdx.x;
    const int b = row & (B_ - 1);
    const float* w0 = bufs + (size_t)row * S_;
    const float* w1 = w0 + (size_t)T_ * B_ * S_;
    float* w = out + (size_t)row * S_;
    const int* mrow = mask + (size_t)b * S_;
    const int tid = threadIdx.x;

    float4 va = *(const float4*)(w0 + tid * 4);
    float4 vb = *(const float4*)(w1 + tid * 4);
    int4 mm = *(const int4*)(mrow + tid * 4);
    float x0 = mm.x ? -INFINITY : (va.x + vb.x);
    float x1 = mm.y ? -INFINITY : (va.y + vb.y);
    float x2 = mm.z ? -INFINITY : (va.z + vb.z);
    float x3 = mm.w ? -INFINITY : (va.w + vb.w);

    float lmax = fmaxf(fmaxf(x0, x1), fmaxf(x2, x3));
#pragma unroll
    for (int off = 32; off >= 1; off >>= 1)
        lmax = fmaxf(lmax, __shfl_down(lmax, off));

    __shared__ float redmax[4];
    __shared__ float redsum[4];
    const int wave = tid >> 6, lane = tid & 63;
    if (lane == 0) redmax[wave] = lmax;
    __syncthreads();
    float gmax = fmaxf(fmaxf(redmax[0], redmax[1]), fmaxf(redmax[2], redmax[3]));

    float e0 = mm.x ? 0.f : __expf(x0 - gmax);
    float e1 = mm.y ? 0.f : __expf(x1 - gmax);
    float e2 = mm.z ? 0.f : __expf(x2 - gmax);
    float e3 = mm.w ? 0.f : __expf(x3 - gmax);
    float lsum = e0 + e1 + e2 + e3;
#pragma unroll
    for (int off = 32; off >= 1; off >>= 1)
        lsum += __shfl_down(lsum, off);
    if (lane == 0) redsum[wave] = lsum;
    __syncthreads();
    float gsum = redsum[0] + redsum[1] + redsum[2] + redsum[3];
    float rinv = 1.0f / gsum;

    *(float4*)(w + tid * 4) = make_float4(e0 * rinv, e1 * rinv, e2 * rinv, e3 * rinv);
}

// ---------------------------------------------------------------------------
extern "C" void kernel_launch(void* const* d_in, const int* in_sizes, int n_in,
                              void* d_out, int out_size, void* d_ws, size_t ws_size,
                              hipStream_t stream) {
    float* src  = (float*)d_in[0];               // (B,S,E) — repacked in-place
    const int* mask = (const int*)d_in[1];       // (B,S)
    const float* qv = (const float*)d_in[2];     // (T,B,Q) fp32
    float* Wsrc = (float*)d_in[3];               // (H*Q,E) — repacked in-place
    const float* Wopt = (const float*)d_in[4];   // (H,Q)
    float* out = (float*)d_out;                  // (T,B,S)

    // ws: bufs = 2 x 16 MiB score partials, then best[] (T*B ints)
    float* bufs = (float*)d_ws;
    int* best = (int*)((char*)d_ws + 2 * (size_t)T_ * B_ * S_ * sizeof(float));

    hipLaunchKernelGGL(prep_kernel, dim3(SRC_BLOCKS + W_BLOCKS + HS_BLOCKS), dim3(256),
                       0, stream, src, Wsrc, qv, Wopt, best);
    hipLaunchKernelGGL(proj_score_kernel, dim3(F_ / 128, M_ / 128), dim3(256), 0, stream,
                       (const unsigned char*)src, (const unsigned char*)Wsrc,
                       qv, best, bufs);
    hipLaunchKernelGGL(softmax_kernel, dim3(T_ * B_), dim3(256), 0, stream,
                       bufs, out, mask);
}